// Round 5
// baseline (118.505 us; speedup 1.0000x reference)
//
#include <hip/hip_runtime.h>
#include <hip/hip_bf16.h>

typedef __bf16 bf16x8 __attribute__((ext_vector_type(8)));
typedef float f32x4 __attribute__((ext_vector_type(4)));
typedef unsigned short ushort8 __attribute__((ext_vector_type(8)));

constexpr int M = 128;             // B*T
constexpr int K = 4096;            // IN
constexpr int N = 11008;           // OUT
constexpr int BN = 32;             // N cols per block
constexpr int BK = 64;             // K per step
constexpr int NT = K / BK;         // 64
constexpr long long NW = (long long)N * K;

// ---------------- pass 1: sum(|W|) ----------------
__global__ __launch_bounds__(256) void absmean_reduce(const float* __restrict__ w,
                                                      double* __restrict__ out_sum)
{
    const int n4 = (int)(NW / 4);
    const float4* w4 = (const float4*)w;
    float s = 0.f;
    for (int i = blockIdx.x * blockDim.x + threadIdx.x; i < n4;
         i += gridDim.x * blockDim.x) {
        float4 v = w4[i];
        s += fabsf(v.x) + fabsf(v.y) + fabsf(v.z) + fabsf(v.w);
    }
#pragma unroll
    for (int off = 32; off > 0; off >>= 1) s += __shfl_down(s, off, 64);
    __shared__ float partial[4];
    if ((threadIdx.x & 63) == 0) partial[threadIdx.x >> 6] = s;
    __syncthreads();
    if (threadIdx.x == 0)
        atomicAdd(out_sum, (double)(partial[0] + partial[1] + partial[2] + partial[3]));
}

__device__ __forceinline__ unsigned short f2bf_bits(float f) {
    unsigned int u = __builtin_bit_cast(unsigned int, f);
    u += 0x7FFFu + ((u >> 16) & 1u);            // RNE to bf16
    return (unsigned short)(u >> 16);
}

// ---------------- pass 2: fused quantize + GEMM (f32 output) ----------------
// 344 blocks x 256 threads (4 waves as 2M x 2N). Block: 128 rows x 32 cols.
__global__ __launch_bounds__(256) void bitlinear_gemm(
    const float* __restrict__ X, const float* __restrict__ W,
    const float* __restrict__ bias, const double* __restrict__ dsum,
    float* __restrict__ out)                    // f32 output (reference dtype)
{
    constexpr int LDSW = 72;                    // shorts per row: 64 + 8 pad
    __shared__ __attribute__((aligned(16))) unsigned short xs[M * LDSW];
    __shared__ __attribute__((aligned(16))) unsigned short wsm[BN * LDSW];

    const float delta = (float)(*dsum / (double)NW + 1e-8);
    const float inv_delta = 1.0f / delta;

    const int tid = threadIdx.x;
    const int lane = tid & 63;
    const int wid = tid >> 6;
    const int wm = wid >> 1;                    // 0..1: 64-row half
    const int wn = wid & 1;                     // 0..1: 16-col half
    const int cgrp = lane >> 4;                 // 0..3
    const int l15 = lane & 15;
    const int n0 = blockIdx.x * BN;

    // staging: thread -> (row sr, 8-elem k-chunk sc)
    const int sr = tid >> 3;                    // 0..31
    const int sc = tid & 7;                     // 0..7
    const int K4 = K / 4;

    const float4* wsrc = (const float4*)(W + (size_t)(n0 + sr) * K) + sc * 2;
    const float4* xbase = (const float4*)X + sc * 2;

    float4 wreg0, wreg1, xreg[4][2];

    // prologue: tile 0 loads
    wreg0 = wsrc[0];
    wreg1 = wsrc[1];
#pragma unroll
    for (int it = 0; it < 4; ++it) {
        const float4* xp = xbase + (size_t)(sr + 32 * it) * K4;
        xreg[it][0] = xp[0];
        xreg[it][1] = xp[1];
    }

    f32x4 acc[4] = {};

    for (int t = 0; t < NT; ++t) {
        __syncthreads();                        // prior tile's LDS reads done
        {   // quantize W (rintf = RNE, matches jnp.round), cvt X to bf16; store LDS
            float wf[8] = {wreg0.x, wreg0.y, wreg0.z, wreg0.w,
                           wreg1.x, wreg1.y, wreg1.z, wreg1.w};
            ushort8 wq;
#pragma unroll
            for (int j = 0; j < 8; ++j) {
                float q = rintf(wf[j] * inv_delta);
                q = fminf(1.f, fmaxf(-1.f, q));
                wq[j] = f2bf_bits(q);           // exact bf16 {-1,0,+1}
            }
            *(ushort8*)&wsm[sr * LDSW + sc * 8] = wq;
#pragma unroll
            for (int it = 0; it < 4; ++it) {
                float xf[8] = {xreg[it][0].x, xreg[it][0].y, xreg[it][0].z, xreg[it][0].w,
                               xreg[it][1].x, xreg[it][1].y, xreg[it][1].z, xreg[it][1].w};
                ushort8 xq;
#pragma unroll
                for (int j = 0; j < 8; ++j) xq[j] = f2bf_bits(xf[j]);
                *(ushort8*)&xs[(sr + 32 * it) * LDSW + sc * 8] = xq;
            }
        }
        __syncthreads();                        // tile t visible
        if (t + 1 < NT) {                       // next tile's globals, overlap MFMA
            const int fo = (t + 1) * (BK / 4);
            wreg0 = wsrc[fo];
            wreg1 = wsrc[fo + 1];
#pragma unroll
            for (int it = 0; it < 4; ++it) {
                const float4* xp = xbase + (size_t)(sr + 32 * it) * K4 + fo;
                xreg[it][0] = xp[0];
                xreg[it][1] = xp[1];
            }
        }
#pragma unroll
        for (int ks = 0; ks < 2; ++ks) {
            const int ch = ks * 4 + cgrp;
            bf16x8 bfr = *(const bf16x8*)&wsm[(wn * 16 + l15) * LDSW + ch * 8];
#pragma unroll
            for (int f = 0; f < 4; ++f) {
                bf16x8 afr = *(const bf16x8*)&xs[(wm * 64 + f * 16 + l15) * LDSW + ch * 8];
                acc[f] = __builtin_amdgcn_mfma_f32_16x16x32_bf16(afr, bfr, acc[f], 0, 0, 0);
            }
        }
    }

    // epilogue: D layout col=lane&15, row=(lane>>4)*4+reg (validated r1==r3)
    const int ocol = n0 + wn * 16 + l15;
    const float bv = bias[ocol];
#pragma unroll
    for (int f = 0; f < 4; ++f) {
        const int mrow = wm * 64 + f * 16 + cgrp * 4;
#pragma unroll
        for (int r = 0; r < 4; ++r)
            out[(size_t)(mrow + r) * N + ocol] = delta * acc[f][r] + bv;
    }
}

extern "C" void kernel_launch(void* const* d_in, const int* in_sizes, int n_in,
                              void* d_out, int out_size, void* d_ws, size_t ws_size,
                              hipStream_t stream) {
    const float* x = (const float*)d_in[0];
    const float* w = (const float*)d_in[1];
    const float* bias = (const float*)d_in[2];
    float* out = (float*)d_out;
    double* dsum = (double*)d_ws;

    hipMemsetAsync(d_ws, 0, sizeof(double), stream);
    absmean_reduce<<<2048, 256, 0, stream>>>(w, dsum);
    bitlinear_gemm<<<N / BN, 256, 0, stream>>>(x, w, bias, dsum, out);
}

// Round 6
// 113.705 us; speedup vs baseline: 1.0422x; 1.0422x over previous
//
#include <hip/hip_runtime.h>
#include <hip/hip_bf16.h>

typedef __bf16 bf16x8 __attribute__((ext_vector_type(8)));
typedef float f32x4 __attribute__((ext_vector_type(4)));
typedef unsigned short ushort8 __attribute__((ext_vector_type(8)));

constexpr int M = 128;             // B*T
constexpr int K = 4096;            // IN
constexpr int N = 11008;           // OUT
constexpr int BN = 32;             // N cols per block
constexpr int BK = 64;             // K per step
constexpr int NT = K / BK;         // 64
constexpr long long NW = (long long)N * K;
constexpr size_t XBF_OFF = 16;     // xbf16 at ws+16 (dsum at ws+0)
constexpr size_t WS_NEED = XBF_OFF + sizeof(unsigned short) * (size_t)M * K;

__device__ __forceinline__ unsigned short f2bf_bits(float f) {
    unsigned int u = __builtin_bit_cast(unsigned int, f);
    u += 0x7FFFu + ((u >> 16) & 1u);            // RNE to bf16
    return (unsigned short)(u >> 16);
}

// ---------------- pass 1: sum(|W|) (+ optional X->bf16 convert) ----------------
template <bool CVT>
__global__ __launch_bounds__(256) void absmean_cvt(const float* __restrict__ w,
                                                   const float* __restrict__ x,
                                                   double* __restrict__ out_sum,
                                                   unsigned short* __restrict__ xbf)
{
    const int gtid = blockIdx.x * blockDim.x + threadIdx.x;
    if (CVT && gtid < M * K / 8) {              // 65536 threads convert 8 elems each
        const float4* xp = (const float4*)x + (size_t)gtid * 2;
        float4 a = xp[0], b = xp[1];
        ushort8 o;
        o[0] = f2bf_bits(a.x); o[1] = f2bf_bits(a.y);
        o[2] = f2bf_bits(a.z); o[3] = f2bf_bits(a.w);
        o[4] = f2bf_bits(b.x); o[5] = f2bf_bits(b.y);
        o[6] = f2bf_bits(b.z); o[7] = f2bf_bits(b.w);
        *(ushort8*)(xbf + (size_t)gtid * 8) = o;
    }
    const int n4 = (int)(NW / 4);
    const float4* w4 = (const float4*)w;
    float s = 0.f;
    for (int i = gtid; i < n4; i += gridDim.x * blockDim.x) {
        float4 v = w4[i];
        s += fabsf(v.x) + fabsf(v.y) + fabsf(v.z) + fabsf(v.w);
    }
#pragma unroll
    for (int off = 32; off > 0; off >>= 1) s += __shfl_down(s, off, 64);
    __shared__ float partial[4];
    if ((threadIdx.x & 63) == 0) partial[threadIdx.x >> 6] = s;
    __syncthreads();
    if (threadIdx.x == 0)
        atomicAdd(out_sum, (double)(partial[0] + partial[1] + partial[2] + partial[3]));
}

// ---------------- pass 2: fused quantize + GEMM, double-buffered ----------------
// 344 blocks x 256 threads (4 waves, 2M x 2N). Block: 128 rows x 32 cols, W read once.
// PRE: X pre-converted bf16 in ws (staging = pure copy). !PRE: inline f32->bf16.
template <bool PRE>
__global__ __launch_bounds__(256) void bitlinear_gemm(
    const void* __restrict__ Xsrc, const float* __restrict__ W,
    const float* __restrict__ bias, const double* __restrict__ dsum,
    float* __restrict__ out)
{
    constexpr int LDSW = 72;                    // 64 + 8 pad shorts (144 B rows)
    __shared__ __attribute__((aligned(16))) unsigned short xs[2][M * LDSW];
    __shared__ __attribute__((aligned(16))) unsigned short wsm[2][BN * LDSW];

    const float delta = (float)(*dsum / (double)NW + 1e-8);
    const float inv_delta = 1.0f / delta;

    const int tid = threadIdx.x;
    const int lane = tid & 63;
    const int wid = tid >> 6;
    const int wm = wid >> 1;                    // 0..1: 64-row half
    const int wn = wid & 1;                     // 0..1: 16-col half
    const int cgrp = lane >> 4;                 // 0..3
    const int l15 = lane & 15;
    const int n0 = blockIdx.x * BN;

    const int sr = tid >> 3;                    // 0..31
    const int sc = tid & 7;                     // 0..7
    const int K4 = K / 4;

    const float4* wsrc = (const float4*)(W + (size_t)(n0 + sr) * K) + sc * 2;
    const unsigned short* xb = (const unsigned short*)Xsrc;   // PRE
    const float4* xf = (const float4*)Xsrc;                   // !PRE

    float4 wr0, wr1;
    ushort8 xr[4];                              // staged X (bf16 bits)

    auto issue = [&](int t) {
        wr0 = wsrc[t * 16];
        wr1 = wsrc[t * 16 + 1];
#pragma unroll
        for (int it = 0; it < 4; ++it) {
            if (PRE) {
                xr[it] = *(const ushort8*)(xb + (size_t)(sr + 32 * it) * K + t * BK + sc * 8);
            } else {
                const float4* xp = xf + (size_t)(sr + 32 * it) * K4 + t * 16 + sc * 2;
                float4 a = xp[0], b = xp[1];
                ushort8 o;
                o[0] = f2bf_bits(a.x); o[1] = f2bf_bits(a.y);
                o[2] = f2bf_bits(a.z); o[3] = f2bf_bits(a.w);
                o[4] = f2bf_bits(b.x); o[5] = f2bf_bits(b.y);
                o[6] = f2bf_bits(b.z); o[7] = f2bf_bits(b.w);
                xr[it] = o;
            }
        }
    };

    auto stage = [&](int buf) {
        float wf[8] = {wr0.x, wr0.y, wr0.z, wr0.w, wr1.x, wr1.y, wr1.z, wr1.w};
        ushort8 wq;
#pragma unroll
        for (int j = 0; j < 8; ++j) {
            float q = rintf(wf[j] * inv_delta);            // RNE, matches jnp.round
            q = fminf(1.f, fmaxf(-1.f, q));
            wq[j] = f2bf_bits(q);                          // exact bf16 {-1,0,+1}
        }
        *(ushort8*)&wsm[buf][sr * LDSW + sc * 8] = wq;
#pragma unroll
        for (int it = 0; it < 4; ++it)
            *(ushort8*)&xs[buf][(sr + 32 * it) * LDSW + sc * 8] = xr[it];
    };

    issue(0);
    stage(0);
    __syncthreads();

    f32x4 acc[4] = {};

    for (int t = 0; t < NT; ++t) {
        const int cur = t & 1;
        if (t + 1 < NT) issue(t + 1);           // global loads in flight over MFMA
#pragma unroll
        for (int ks = 0; ks < 2; ++ks) {
            const int ch = ks * 4 + cgrp;
            bf16x8 bfr = *(const bf16x8*)&wsm[cur][(wn * 16 + l15) * LDSW + ch * 8];
#pragma unroll
            for (int f = 0; f < 4; ++f) {
                bf16x8 afr = *(const bf16x8*)&xs[cur][(wm * 64 + f * 16 + l15) * LDSW + ch * 8];
                acc[f] = __builtin_amdgcn_mfma_f32_16x16x32_bf16(afr, bfr, acc[f], 0, 0, 0);
            }
        }
        if (t + 1 < NT) stage(cur ^ 1);         // vmcnt waits land here, not at barrier top
        __syncthreads();                        // ONE barrier per K-step
    }

    // epilogue: D col=lane&15, row=(lane>>4)*4+reg (validated)
    const int ocol = n0 + wn * 16 + l15;
    const float bv = bias[ocol];
#pragma unroll
    for (int f = 0; f < 4; ++f) {
        const int mrow = wm * 64 + f * 16 + cgrp * 4;
#pragma unroll
        for (int r = 0; r < 4; ++r)
            out[(size_t)(mrow + r) * N + ocol] = delta * acc[f][r] + bv;
    }
}

extern "C" void kernel_launch(void* const* d_in, const int* in_sizes, int n_in,
                              void* d_out, int out_size, void* d_ws, size_t ws_size,
                              hipStream_t stream) {
    const float* x = (const float*)d_in[0];
    const float* w = (const float*)d_in[1];
    const float* bias = (const float*)d_in[2];
    float* out = (float*)d_out;
    double* dsum = (double*)d_ws;
    unsigned short* xbf = (unsigned short*)((char*)d_ws + XBF_OFF);

    hipMemsetAsync(d_ws, 0, sizeof(double), stream);
    if (ws_size >= WS_NEED) {
        absmean_cvt<true><<<2048, 256, 0, stream>>>(w, x, dsum, xbf);
        bitlinear_gemm<true><<<N / BN, 256, 0, stream>>>(xbf, w, bias, dsum, out);
    } else {
        absmean_cvt<false><<<2048, 256, 0, stream>>>(w, x, dsum, xbf);
        bitlinear_gemm<false><<<N / BN, 256, 0, stream>>>(x, w, bias, dsum, out);
    }
}

// Round 7
// 75.000 us; speedup vs baseline: 1.5801x; 1.5161x over previous
//
#include <hip/hip_runtime.h>
#include <hip/hip_bf16.h>

typedef __bf16 bf16x8 __attribute__((ext_vector_type(8)));
typedef float f32x4 __attribute__((ext_vector_type(4)));
typedef unsigned short ushort8 __attribute__((ext_vector_type(8)));

constexpr int M = 128;             // B*T
constexpr int K = 4096;            // IN
constexpr int N = 11008;           // OUT
constexpr int BN = 32;             // N cols per block
constexpr int BK = 64;             // K per step
constexpr long long NW = (long long)N * K;
constexpr int RBLK = 2048;         // reduce blocks

// ws layout
constexpr size_t PART_OFF = 0;                              // 2048 f32 partials
constexpr size_t XBF_OFF  = 8192;                           // X as bf16 (1 MB)
constexpr size_t P0_OFF   = XBF_OFF + (size_t)M * K * 2;    // split-0 partial out
constexpr size_t PSZ      = (size_t)M * N * sizeof(float);  // 5.636 MB
constexpr size_t P1_OFF   = P0_OFF + PSZ;
constexpr size_t WS_NEED  = P1_OFF + PSZ;

__device__ __forceinline__ unsigned short f2bf_bits(float f) {
    unsigned int u = __builtin_bit_cast(unsigned int, f);
    u += 0x7FFFu + ((u >> 16) & 1u);            // RNE to bf16
    return (unsigned short)(u >> 16);
}

// ---- pass 1: per-block partial sum of |W| (NO atomics) + X->bf16 convert ----
template <bool CVT>
__global__ __launch_bounds__(256) void absmean_partial(const float* __restrict__ w,
                                                       const float* __restrict__ x,
                                                       float* __restrict__ partials,
                                                       unsigned short* __restrict__ xbf)
{
    const int gtid = blockIdx.x * blockDim.x + threadIdx.x;
    if (CVT && gtid < M * K / 8) {
        const float4* xp = (const float4*)x + (size_t)gtid * 2;
        float4 a = xp[0], b = xp[1];
        ushort8 o;
        o[0] = f2bf_bits(a.x); o[1] = f2bf_bits(a.y);
        o[2] = f2bf_bits(a.z); o[3] = f2bf_bits(a.w);
        o[4] = f2bf_bits(b.x); o[5] = f2bf_bits(b.y);
        o[6] = f2bf_bits(b.z); o[7] = f2bf_bits(b.w);
        *(ushort8*)(xbf + (size_t)gtid * 8) = o;
    }
    const int n4 = (int)(NW / 4);
    const float4* w4 = (const float4*)w;
    float s0 = 0.f, s1 = 0.f, s2 = 0.f, s3 = 0.f;
    for (int i = gtid; i < n4; i += gridDim.x * blockDim.x) {
        float4 v = w4[i];
        s0 += fabsf(v.x); s1 += fabsf(v.y); s2 += fabsf(v.z); s3 += fabsf(v.w);
    }
    float s = (s0 + s1) + (s2 + s3);
#pragma unroll
    for (int off = 32; off > 0; off >>= 1) s += __shfl_down(s, off, 64);
    __shared__ float red[4];
    if ((threadIdx.x & 63) == 0) red[threadIdx.x >> 6] = s;
    __syncthreads();
    if (threadIdx.x == 0)
        partials[blockIdx.x] = (red[0] + red[1]) + (red[2] + red[3]);
}

// ---- pass 2: fused quantize + GEMM ----
// KSTEPS=32,!DIRECT: grid(344,2) K-split, partial products to ws (no bias)
// KSTEPS=64, DIRECT: grid(344),  full K, out = delta*acc + bias (fallback)
template <int KSTEPS, bool DIRECT>
__global__ __launch_bounds__(256) void bitlinear_gemm(
    const void* __restrict__ Xsrc, const float* __restrict__ W,
    const float* __restrict__ bias, const float* __restrict__ partials,
    float* __restrict__ dbase)
{
    constexpr int LDSW = 72;                    // 64 + 8 pad shorts (144 B rows)
    __shared__ __attribute__((aligned(16))) unsigned short xs[2][M * LDSW];
    __shared__ __attribute__((aligned(16))) unsigned short wsm[2][BN * LDSW];

    const int tid = threadIdx.x;
    const int lane = tid & 63;
    const int wid = tid >> 6;
    const int wm = wid >> 1;                    // 0..1: 64-row half
    const int wn = wid & 1;                     // 0..1: 16-col half
    const int cgrp = lane >> 4;                 // 0..3
    const int l15 = lane & 15;
    const int n0 = blockIdx.x * BN;
    const int kk0 = DIRECT ? 0 : blockIdx.y * KSTEPS;   // K-step origin

    const int sr = tid >> 3;                    // 0..31
    const int sc = tid & 7;                     // 0..7
    const int K4 = K / 4;

    const float4* wsrc = (const float4*)(W + (size_t)(n0 + sr) * K) + sc * 2;
    const unsigned short* xb = (const unsigned short*)Xsrc;
    const float4* xf = (const float4*)Xsrc;

    float4 wr0, wr1;
    ushort8 xr[4];

    auto issue = [&](int t) {
        const int g = kk0 + t;
        wr0 = wsrc[g * 16];
        wr1 = wsrc[g * 16 + 1];
#pragma unroll
        for (int it = 0; it < 4; ++it) {
            if (!DIRECT) {
                xr[it] = *(const ushort8*)(xb + (size_t)(sr + 32 * it) * K + g * BK + sc * 8);
            } else {
                const float4* xp = xf + (size_t)(sr + 32 * it) * K4 + g * 16 + sc * 2;
                float4 a = xp[0], b = xp[1];
                ushort8 o;
                o[0] = f2bf_bits(a.x); o[1] = f2bf_bits(a.y);
                o[2] = f2bf_bits(a.z); o[3] = f2bf_bits(a.w);
                o[4] = f2bf_bits(b.x); o[5] = f2bf_bits(b.y);
                o[6] = f2bf_bits(b.z); o[7] = f2bf_bits(b.w);
                xr[it] = o;
            }
        }
    };

    // tile-0 loads first, then delta reduce (loads stay in flight over it)
    issue(0);

    float s = 0.f;
#pragma unroll
    for (int i = 0; i < RBLK / 256; ++i) s += partials[tid + i * 256];
#pragma unroll
    for (int off = 32; off > 0; off >>= 1) s += __shfl_down(s, off, 64);
    __shared__ float red[4];
    if (lane == 0) red[wid] = s;
    __syncthreads();
    const float delta =
        (float)((double)((red[0] + red[1]) + (red[2] + red[3])) / (double)NW + 1e-8);
    const float inv_delta = 1.0f / delta;

    auto stage = [&](int buf) {
        float wf[8] = {wr0.x, wr0.y, wr0.z, wr0.w, wr1.x, wr1.y, wr1.z, wr1.w};
        ushort8 wq;
#pragma unroll
        for (int j = 0; j < 8; ++j) {
            float q = rintf(wf[j] * inv_delta);            // RNE = jnp.round
            q = fminf(1.f, fmaxf(-1.f, q));
            wq[j] = f2bf_bits(q);                          // exact bf16 {-1,0,+1}
        }
        *(ushort8*)&wsm[buf][sr * LDSW + sc * 8] = wq;
#pragma unroll
        for (int it = 0; it < 4; ++it)
            *(ushort8*)&xs[buf][(sr + 32 * it) * LDSW + sc * 8] = xr[it];
    };

    stage(0);
    __syncthreads();

    f32x4 acc[4] = {};

    for (int t = 0; t < KSTEPS; ++t) {
        const int cur = t & 1;
        if (t + 1 < KSTEPS) issue(t + 1);
#pragma unroll
        for (int ks = 0; ks < 2; ++ks) {
            const int ch = ks * 4 + cgrp;
            bf16x8 bfr = *(const bf16x8*)&wsm[cur][(wn * 16 + l15) * LDSW + ch * 8];
#pragma unroll
            for (int f = 0; f < 4; ++f) {
                bf16x8 afr = *(const bf16x8*)&xs[cur][(wm * 64 + f * 16 + l15) * LDSW + ch * 8];
                acc[f] = __builtin_amdgcn_mfma_f32_16x16x32_bf16(afr, bfr, acc[f], 0, 0, 0);
            }
        }
        if (t + 1 < KSTEPS) stage(cur ^ 1);
        __syncthreads();
    }

    // epilogue: D col=lane&15, row=(lane>>4)*4+reg (validated)
    float* dst = DIRECT ? dbase : dbase + (size_t)blockIdx.y * ((size_t)M * N);
    const int ocol = n0 + wn * 16 + l15;
    const float bv = DIRECT ? bias[ocol] : 0.f;
#pragma unroll
    for (int f = 0; f < 4; ++f) {
        const int mrow = wm * 64 + f * 16 + cgrp * 4;
#pragma unroll
        for (int r = 0; r < 4; ++r)
            dst[(size_t)(mrow + r) * N + ocol] = delta * acc[f][r] + bv;
    }
}

// ---- pass 3: out = p0 + p1 + bias ----
__global__ __launch_bounds__(256) void combine(const float4* __restrict__ p0,
                                               const float4* __restrict__ p1,
                                               const float* __restrict__ bias,
                                               float4* __restrict__ out)
{
    const int i4 = blockIdx.x * blockDim.x + threadIdx.x;
    constexpr int N4 = N / 4;                   // 2752
    if (i4 >= M * N4) return;
    const int col4 = i4 % N4;
    const float4 b = *(const float4*)(bias + col4 * 4);
    float4 a = p0[i4], c = p1[i4];
    float4 o;
    o.x = a.x + c.x + b.x; o.y = a.y + c.y + b.y;
    o.z = a.z + c.z + b.z; o.w = a.w + c.w + b.w;
    out[i4] = o;
}

extern "C" void kernel_launch(void* const* d_in, const int* in_sizes, int n_in,
                              void* d_out, int out_size, void* d_ws, size_t ws_size,
                              hipStream_t stream) {
    const float* x = (const float*)d_in[0];
    const float* w = (const float*)d_in[1];
    const float* bias = (const float*)d_in[2];
    float* out = (float*)d_out;
    float* partials = (float*)((char*)d_ws + PART_OFF);
    unsigned short* xbf = (unsigned short*)((char*)d_ws + XBF_OFF);
    float* p0 = (float*)((char*)d_ws + P0_OFF);
    float* p1 = (float*)((char*)d_ws + P1_OFF);

    if (ws_size >= WS_NEED) {
        absmean_partial<true><<<RBLK, 256, 0, stream>>>(w, x, partials, xbf);
        bitlinear_gemm<32, false><<<dim3(N / BN, 2), 256, 0, stream>>>(
            xbf, w, bias, partials, p0);
        combine<<<(M * N / 4 + 255) / 256, 256, 0, stream>>>(
            (const float4*)p0, (const float4*)p1, bias, (float4*)out);
    } else {
        absmean_partial<false><<<RBLK, 256, 0, stream>>>(w, x, partials, xbf);
        bitlinear_gemm<64, true><<<N / BN, 256, 0, stream>>>(
            x, w, bias, partials, out);
    }
}